// Round 1
// 56.779 us; speedup vs baseline: 1.5975x; 1.5975x over previous
//
#include <hip/hip_runtime.h>

// SelfAttention3D: B=4, C=128, N=16^3=4096, Cqk=16.
// R5: memory-path fix on top of R4.
//  (a) XCD-batch swizzle in BOTH kernels: blocks round-robin XCDs, so
//      b=(bid&7)>>1 pins each batch to one XCD pair -> per-XCD L2 working
//      set drops from ~4.6MB (thrash) to ~1.3MB (resident), and proj's
//      output lines are consumed from the same XCD's L2.
//  (b) V re-tiled in workspace as [b][c>>4][m>>5][(m>>3)&3][c&15][8elem]
//      so each attn V-fragment load is ONE contiguous 1KB wave transaction
//      instead of 16 x 64B segments 8KB apart.

typedef __attribute__((ext_vector_type(8))) short short8;
typedef __attribute__((ext_vector_type(4))) float f32x4;

#define NTOK 4096
#define CDIM 128

__device__ __forceinline__ unsigned short f2bf(float f) {
  unsigned int u = __float_as_uint(f);
  return (unsigned short)((u + 0x7fffu + ((u >> 16) & 1u)) >> 16);
}

// ---------------------------------------------------------------------------
// Projection: q,k,v channel-GEMMs, bf16 outputs.
// qb,kb: [B][N][16] row per token; vb: tiled layout (see header comment).
// ---------------------------------------------------------------------------
__global__ __launch_bounds__(256) void sa3d_proj(
    const float* __restrict__ x,
    const float* __restrict__ Wq, const float* __restrict__ bq,
    const float* __restrict__ Wk, const float* __restrict__ bk,
    const float* __restrict__ Wv, const float* __restrict__ bv,
    unsigned short* __restrict__ qb, unsigned short* __restrict__ kb,
    unsigned short* __restrict__ vb)
{
  __shared__ unsigned short Wl[160 * 136];
  __shared__ unsigned short xT[64 * 136];
  const int tid = threadIdx.x;
  // XCD swizzle: xcd = bid&7 (round-robin heuristic), batch = xcd>>1.
  const int b = (blockIdx.x & 7) >> 1;
  const int nt = ((blockIdx.x >> 3) << 1) | (blockIdx.x & 1);  // [0,64)
  const int n0 = nt << 6;

  for (int i = 0; i < 80; ++i) {
    int idx = i * 256 + tid;
    int o = idx >> 7, c = idx & 127;
    float wv;
    if (o < 16)      wv = Wq[o * 128 + c];
    else if (o < 32) wv = Wk[(o - 16) * 128 + c];
    else             wv = Wv[(o - 32) * 128 + c];
    Wl[o * 136 + c] = f2bf(wv);
  }
  {
    int nn = tid & 63, cg = tid >> 6;
    const float* xp = x + (size_t)b * CDIM * NTOK + n0 + nn;
    for (int cp = 0; cp < 16; ++cp) {
      int c = cg * 32 + cp * 2;
      float v0 = xp[(size_t)c * NTOK];
      float v1 = xp[(size_t)(c + 1) * NTOK];
      *(unsigned int*)&xT[nn * 136 + c] =
          (unsigned int)f2bf(v0) | ((unsigned int)f2bf(v1) << 16);
    }
  }
  __syncthreads();

  const int w = tid >> 6, lane = tid & 63;
  const int l15 = lane & 15, g = lane >> 4;

  short8 bfr[4];
#pragma unroll
  for (int ks = 0; ks < 4; ++ks)
    bfr[ks] = *(const short8*)&xT[(w * 16 + l15) * 136 + ks * 32 + g * 8];

  const int n = n0 + w * 16 + l15;
#pragma unroll
  for (int ot = 0; ot < 10; ++ot) {
    f32x4 acc = {};
#pragma unroll
    for (int ks = 0; ks < 4; ++ks) {
      short8 af = *(const short8*)&Wl[(ot * 16 + l15) * 136 + ks * 32 + g * 8];
      acc = __builtin_amdgcn_mfma_f32_16x16x32_bf16(af, bfr[ks], acc, 0, 0, 0);
    }
    int ob = ot * 16 + 4 * g;
    if (ot == 0) {
      unsigned int p0 = (unsigned int)f2bf(acc[0] + bq[ob]) |
                        ((unsigned int)f2bf(acc[1] + bq[ob + 1]) << 16);
      unsigned int p1 = (unsigned int)f2bf(acc[2] + bq[ob + 2]) |
                        ((unsigned int)f2bf(acc[3] + bq[ob + 3]) << 16);
      unsigned int* d = (unsigned int*)&qb[((size_t)b * NTOK + n) * 16 + ob];
      d[0] = p0; d[1] = p1;
    } else if (ot == 1) {
      int o2 = ob - 16;
      unsigned int p0 = (unsigned int)f2bf(acc[0] + bk[o2]) |
                        ((unsigned int)f2bf(acc[1] + bk[o2 + 1]) << 16);
      unsigned int p1 = (unsigned int)f2bf(acc[2] + bk[o2 + 2]) |
                        ((unsigned int)f2bf(acc[3] + bk[o2 + 3]) << 16);
      unsigned int* d = (unsigned int*)&kb[((size_t)b * NTOK + n) * 16 + o2];
      d[0] = p0; d[1] = p1;
    } else {
#pragma unroll
      for (int r = 0; r < 4; ++r) {
        int o = ob + r - 32;  // channel c in [0,128)
        // tiled V: elem(c,m) = (c>>4)*65536 + (m>>5)*512 + ((m>>3)&3)*128
        //                      + (c&15)*8 + (m&7)
        size_t eidx = (size_t)(o >> 4) * 65536 + (size_t)(n >> 5) * 512 +
                      (size_t)((n >> 3) & 3) * 128 + (o & 15) * 8 + (n & 7);
        vb[(size_t)b * (CDIM * NTOK) + eidx] = f2bf(acc[r] + bv[o]);
      }
    }
  }
}

// ---------------------------------------------------------------------------
// Flash attention. 512 blocks x 512 threads (8 waves), no in-loop barriers.
// Block: batch b = (bid&7)>>1 (XCD-pinned), 32 queries; wave w owns keys
// [w*512,(w+1)*512). Per iter: vf[16] register-staged V (coalesced 1KB
// loads), K ping-pong prefetch, per-wave LDS P.
// End: LDS tree-reduce of 8 waves' (acc,L), wave-0 epilogue gamma*acc/L + x.
// ---------------------------------------------------------------------------
__global__ __launch_bounds__(512, 2) void sa3d_attn(
    const unsigned short* __restrict__ qb, const unsigned short* __restrict__ kb,
    const unsigned short* __restrict__ vb,
    const float* __restrict__ x, const float* __restrict__ gamma,
    float* __restrict__ out)
{
  // LDS: [0,36864): 8 per-wave P buffers (32 rows x 72 shorts = 4608 B each)
  //      [0,65536): 4 reduce slots of 16 KB (reused after loop)
  //      [65536,66560): L reduce area, 4 slots x 32 floats
  __shared__ __align__(16) unsigned char smem[66560];

  const int tid = threadIdx.x;
  const int w = tid >> 6, lane = tid & 63;
  const int l15 = lane & 15, g = lane >> 4;
  const int b = (blockIdx.x & 7) >> 1;
  const int qt = ((blockIdx.x >> 3) << 1) | (blockIdx.x & 1);  // [0,128)
  const int q0 = qt << 5;

  unsigned short* PLw = (unsigned short*)smem + w * 2304;  // 32 x 72 shorts
  float* LDp = (float*)(smem + 65536);

  const unsigned short* qbase = qb + (size_t)b * NTOK * 16;
  const unsigned short* kbase = kb + (size_t)b * NTOK * 16;
  const unsigned short* vbase = vb + (size_t)b * CDIM * NTOK;

  short8 aq[2] = {short8{}, short8{}};
#pragma unroll
  for (int qh = 0; qh < 2; ++qh)
    if (g < 2)
      aq[qh] = *(const short8*)&qbase[(size_t)(q0 + qh * 16 + l15) * 16 + g * 8];

  f32x4 acc[16];  // [qh*8 + ct]
#pragma unroll
  for (int i = 0; i < 16; ++i) acc[i] = (f32x4){};
  float Lp[2][4] = {{0.f, 0.f, 0.f, 0.f}, {0.f, 0.f, 0.f, 0.f}};

  const int kv0 = w << 9;  // 512 keys per wave

  // K prefetch for tile 0
  short8 kfa[4], kfb[4];
#pragma unroll
  for (int kt = 0; kt < 4; ++kt) {
    kfa[kt] = short8{};
    if (g < 2)
      kfa[kt] = *(const short8*)&kbase[(size_t)(kv0 + kt * 16 + l15) * 16 + g * 8];
  }

  // One KV-tile iteration: V reg-stage -> QK/exp/P-write -> K prefetch -> PV.
  // V tiled layout: fragment (ch,ct) at elem ct*65536 + (mb5+ch)*512
  //                 + g*128 + l15*8  -> one contiguous 1KB per wave-load.
#define SA_ITER(T, KC, KN)                                                    \
  {                                                                           \
    const int m0 = kv0 + ((T) << 6);                                          \
    const int mb5 = m0 >> 5;                                                  \
    short8 vf[16];                                                            \
    _Pragma("unroll") for (int ch = 0; ch < 2; ++ch)                          \
      _Pragma("unroll") for (int ct = 0; ct < 8; ++ct)                        \
        vf[ch * 8 + ct] = *(const short8*)&vbase[(size_t)ct * 65536 +         \
                                                 (size_t)(mb5 + ch) * 512 +   \
                                                 g * 128 + l15 * 8];          \
    _Pragma("unroll") for (int kt = 0; kt < 4; ++kt) {                        \
      _Pragma("unroll") for (int qh = 0; qh < 2; ++qh) {                      \
        f32x4 zero = {};                                                      \
        f32x4 s = __builtin_amdgcn_mfma_f32_16x16x32_bf16(aq[qh], KC[kt],     \
                                                          zero, 0, 0, 0);     \
        _Pragma("unroll") for (int r = 0; r < 4; ++r) {                       \
          float e = __expf(s[r]);                                             \
          Lp[qh][r] += e;                                                     \
          PLw[(qh * 16 + 4 * g + r) * 72 + kt * 16 + l15] = f2bf(e);          \
        }                                                                     \
      }                                                                       \
    }                                                                         \
    const int mn = kv0 + (((T) + 1 < 8 ? (T) + 1 : 0) << 6);                  \
    _Pragma("unroll") for (int kt = 0; kt < 4; ++kt) {                        \
      KN[kt] = short8{};                                                      \
      if (g < 2)                                                              \
        KN[kt] = *(const short8*)&kbase[(size_t)(mn + kt * 16 + l15) * 16 +   \
                                        g * 8];                               \
    }                                                                         \
    _Pragma("unroll") for (int ch = 0; ch < 2; ++ch) {                        \
      short8 pa0 = *(const short8*)&PLw[l15 * 72 + ch * 32 + g * 8];          \
      short8 pa1 = *(const short8*)&PLw[(16 + l15) * 72 + ch * 32 + g * 8];   \
      _Pragma("unroll") for (int ct = 0; ct < 8; ++ct) {                      \
        acc[ct] = __builtin_amdgcn_mfma_f32_16x16x32_bf16(pa0, vf[ch * 8 + ct], \
                                                          acc[ct], 0, 0, 0); \
        acc[8 + ct] = __builtin_amdgcn_mfma_f32_16x16x32_bf16(                \
            pa1, vf[ch * 8 + ct], acc[8 + ct], 0, 0, 0);                      \
      }                                                                       \
    }                                                                         \
  }

  for (int tt = 0; tt < 4; ++tt) {
    SA_ITER(tt * 2, kfa, kfb);
    SA_ITER(tt * 2 + 1, kfb, kfa);
  }
#undef SA_ITER

  // intra-wave L reduce over the 16 l15 lanes
#pragma unroll
  for (int qh = 0; qh < 2; ++qh)
#pragma unroll
    for (int r = 0; r < 4; ++r) {
      float v = Lp[qh][r];
      v += __shfl_xor(v, 1);
      v += __shfl_xor(v, 2);
      v += __shfl_xor(v, 4);
      v += __shfl_xor(v, 8);
      Lp[qh][r] = v;
    }

  // cross-wave tree reduce: 8 -> 4 -> 2 -> 1 (XOR-swizzled 256B rows)
  const int rowb = lane * 256;
  const int sw = (l15) << 4;

#define ACC_STORE(i)                                                        \
  {                                                                         \
    char* base = (char*)smem + (i) * 16384 + rowb;                          \
    _Pragma("unroll") for (int j = 0; j < 16; ++j)                          \
        *(f32x4*)(base + ((j * 16) ^ sw)) = acc[j];                         \
    if (l15 == 0) {                                                         \
      _Pragma("unroll") for (int qh = 0; qh < 2; ++qh)                      \
          _Pragma("unroll") for (int r = 0; r < 4; ++r)                     \
              LDp[(i) * 32 + qh * 16 + 4 * g + r] = Lp[qh][r];              \
    }                                                                       \
  }
#define ACC_ADD(i)                                                          \
  {                                                                         \
    char* base = (char*)smem + (i) * 16384 + rowb;                          \
    _Pragma("unroll") for (int j = 0; j < 16; ++j)                          \
        acc[j] += *(const f32x4*)(base + ((j * 16) ^ sw));                  \
    _Pragma("unroll") for (int qh = 0; qh < 2; ++qh)                        \
        _Pragma("unroll") for (int r = 0; r < 4; ++r)                       \
            Lp[qh][r] += LDp[(i) * 32 + qh * 16 + 4 * g + r];               \
  }

  __syncthreads();
  if (w >= 4) ACC_STORE(w - 4);
  __syncthreads();
  if (w < 4) ACC_ADD(w);
  __syncthreads();
  if (w == 2 || w == 3) ACC_STORE(w - 2);
  __syncthreads();
  if (w < 2) ACC_ADD(w);
  __syncthreads();
  if (w == 1) ACC_STORE(0);
  __syncthreads();

  if (w == 0) {
    ACC_ADD(0);
    const float ga = gamma[0];
    float inv[2][4];
#pragma unroll
    for (int qh = 0; qh < 2; ++qh)
#pragma unroll
      for (int r = 0; r < 4; ++r) inv[qh][r] = 1.0f / Lp[qh][r];

    const float* xb = x + (size_t)b * CDIM * NTOK;
    float* ob = out + (size_t)b * CDIM * NTOK;
#pragma unroll
    for (int qh = 0; qh < 2; ++qh)
#pragma unroll
      for (int ct = 0; ct < 8; ++ct) {
        int c = ct * 16 + l15;
        size_t idx = (size_t)c * NTOK + q0 + qh * 16 + 4 * g;
        f32x4 xv = *(const f32x4*)&xb[idx];
        f32x4 o;
#pragma unroll
        for (int r = 0; r < 4; ++r)
          o[r] = ga * acc[qh * 8 + ct][r] * inv[qh][r] + xv[r];
        *(f32x4*)&ob[idx] = o;
      }
  }
}

extern "C" void kernel_launch(void* const* d_in, const int* in_sizes, int n_in,
                              void* d_out, int out_size, void* d_ws, size_t ws_size,
                              hipStream_t stream) {
  const float* x     = (const float*)d_in[0];
  const float* Wq    = (const float*)d_in[1];
  const float* bq    = (const float*)d_in[2];
  const float* Wk    = (const float*)d_in[3];
  const float* bk    = (const float*)d_in[4];
  const float* Wv    = (const float*)d_in[5];
  const float* bv    = (const float*)d_in[6];
  const float* gamma = (const float*)d_in[7];

  unsigned short* qb = (unsigned short*)d_ws;          // 512 KB
  unsigned short* kb = qb + (size_t)4 * NTOK * 16;     // 512 KB
  unsigned short* vb = kb + (size_t)4 * NTOK * 16;     // 4 MB (tiled layout)
  float* outp = (float*)d_out;

  sa3d_proj<<<dim3(256), dim3(256), 0, stream>>>(x, Wq, bq, Wk, bk, Wv, bv,
                                                 qb, kb, vb);
  sa3d_attn<<<dim3(512), dim3(512), 0, stream>>>(qb, kb, vb, x, gamma, outp);
}